// Round 13
// baseline (337.018 us; speedup 1.0000x reference)
//
#include <hip/hip_runtime.h>

typedef unsigned int u32;
typedef unsigned short u16;
typedef short short8v __attribute__((ext_vector_type(8)));
typedef float f32x4 __attribute__((ext_vector_type(4)));

#define ND 1024
#define NH 16
#define OUT_T ((size_t)16777216)  // 2*16*8192*64 elements per stacked tensor

__device__ __forceinline__ u16 f2bf(float f) {
  u32 u = __float_as_uint(f);
  u32 r = u + 0x7fffu + ((u >> 16) & 1u);
  return (u16)(r >> 16);
}

__device__ __forceinline__ short8v pack8(float4 a, float4 b) {
  short8v v;
  v[0] = (short)f2bf(a.x); v[1] = (short)f2bf(a.y);
  v[2] = (short)f2bf(a.z); v[3] = (short)f2bf(a.w);
  v[4] = (short)f2bf(b.x); v[5] = (short)f2bf(b.y);
  v[6] = (short)f2bf(b.z); v[7] = (short)f2bf(b.w);
  return v;
}

__device__ __forceinline__ void gload16(const void* g, void* l) {
  __builtin_amdgcn_global_load_lds((const __attribute__((address_space(1))) void*)g,
                                   (__attribute__((address_space(3))) void*)l, 16, 0, 0);
}

// ---- kernel 0: weights -> WT2[w][h][kc][c][8] bf16 (K-chunk-major, coalesced B frags) ----
__global__ void k_wt(const float* __restrict__ w0, const float* __restrict__ w1,
                     const float* __restrict__ w2, const float* __restrict__ w3,
                     u16* __restrict__ WT) {
  __shared__ float T[64][65];
  int bid = blockIdx.x;
  int w = bid >> 8;
  int tk = (bid >> 4) & 15, tc = bid & 15;   // tc == head h (64-col tiles)
  const float* W = w == 0 ? w0 : w == 1 ? w1 : w == 2 ? w2 : w3;
  int k0 = tk << 6, c0 = tc << 6;
  int tid = threadIdx.x;
  for (int it = 0; it < 16; ++it) {
    int idx = it * 256 + tid;
    int kk = idx >> 6, cc = idx & 63;
    T[kk][cc] = W[(size_t)(k0 + kk) * ND + c0 + cc];
  }
  __syncthreads();
  for (int it = 0; it < 2; ++it) {
    int ci = it * 256 + tid;
    int cc = ci >> 3, k8 = ci & 7;
    short8v v;
    for (int j = 0; j < 8; ++j) v[j] = (short)f2bf(T[k8 * 8 + j][cc]);
    size_t off = ((((size_t)(w * 16 + tc) * 128) + (tk << 3) + k8) * 64 + cc) * 8;
    *(short8v*)(WT + off) = v;
  }
}

// ---- kernel 0b: X f32 -> bf16 ----
__global__ void k_xbf(const float* __restrict__ X, u16* __restrict__ Xb) {
  size_t i = ((size_t)blockIdx.x * 256 + threadIdx.x) * 8;
  float4 a = *(const float4*)(X + i), b = *(const float4*)(X + i + 4);
  *(short8v*)(Xb + i) = pack8(a, b);
}

// ---- kernel 1: lr proj via MFMA + sigmoid + direct eta writes ----
__global__ __launch_bounds__(256) void k_lr2(const u16* __restrict__ Xb,
                                             const float* __restrict__ LW,
                                             const float* __restrict__ LB,
                                             float* __restrict__ out) {
  __shared__ __align__(16) char smem[46080];
  u16* LWs = (u16*)smem;               // [16][1024] bf16, chunk-swizzled (32KB)
  u16* As = (u16*)(smem + 32768);      // [64][64] bf16, chunk-swizzled (8KB)
  float* El = (float*)(smem + 40960);  // [16 h][72] f32
  const int tid = threadIdx.x, lane = tid & 63, wid = tid >> 6;
  const int l15 = lane & 15, lg = lane >> 4;
  const int n = blockIdx.x;            // global chunk 0..255
  const int tok0 = n << 6;

  {
    int row = tid >> 4;
    int cbase = (tid & 15) << 3;
    const float* src = LW + row * ND + (cbase << 3);
    for (int i = 0; i < 8; ++i) {
      float4 a = *(const float4*)(src + i * 8);
      float4 b = *(const float4*)(src + i * 8 + 4);
      int sc = (cbase + i) ^ (row & 7);
      *(short8v*)(LWs + row * 1024 + (sc << 3)) = pack8(a, b);
    }
  }

  const int arow0 = (wid << 4) + (lane >> 3);
  const u16* asrc = Xb + (size_t)(tok0 + arow0) * ND + ((((lane & 7) ^ arow0) & 7) << 3);
  const u32 aldo = wid << 10;
  const int aoff = ((wid << 4) + l15) << 6;
  const int key = l15 & 7;

  f32x4 acc;
  for (int r = 0; r < 4; ++r) acc[r] = 0.f;
  __syncthreads();

  for (int kt = 0; kt < 16; ++kt) {
    gload16(asrc + (kt << 6), As + aldo);
    gload16(asrc + (kt << 6) + 8 * ND, As + aldo + 512);
    __syncthreads();
    for (int ks = 0; ks < 2; ++ks) {
      int kcl = (ks << 2) + lg;
      int kcg = (kt << 3) + kcl;
      short8v af = *(const short8v*)(As + aoff + ((kcl ^ key) << 3));
      short8v bf = *(const short8v*)(LWs + (l15 << 10) + ((kcg ^ key) << 3));
      acc = __builtin_amdgcn_mfma_f32_16x16x32_bf16(af, bf, acc, 0, 0, 0);
    }
    __syncthreads();
  }

  for (int rr = 0; rr < 4; ++rr) {
    float v = acc[rr] + LB[l15];
    float e = (1.f / (1.f + expf(-v))) * (1.f / 4096.f);
    El[l15 * 72 + (wid << 4) + (lg << 2) + rr] = e;
  }
  __syncthreads();

  const int b = n >> 7, nl = n & 127;
  int q, rc;
  if (nl < 4) { q = nl; rc = 0; }
  else { q = (nl - 4) / 31; rc = nl - 3 - 31 * q; }
  const int pc = q * 32 + rc;
  const int j = tid >> 2, kq = tid & 3;
  size_t base = 4 * OUT_T + (((size_t)(b * NH) << 13) + (pc << 6)) * 64 + (size_t)j * 64;
  for (int h = 0; h < 16; ++h) {
    float* po = out + base + ((size_t)h << 19);
    for (int qq = 0; qq < 4; ++qq) {
      int k0 = (kq + (qq << 2)) << 2;
      const float* ep = El + h * 72 + k0;
      f32x4 t; t[0] = ep[0]; t[1] = ep[1]; t[2] = ep[2]; t[3] = ep[3];
      *(f32x4*)(po + k0) = t;
    }
  }
}

// ---- kernel 2: main fused GEMM; ZERO-barrier K-loop, both operands direct
// from L1/L2 into registers (no LDS staging). 256 thr (4 waves), wave w =
// weight w, tile 128 tokens x 256 cols. Epilogue via LDS Cs (barriers only there).
__global__ __launch_bounds__(256, 2) void k_main(
    const u16* __restrict__ Xb, const float* __restrict__ FC,
    const u16* __restrict__ WT,
    const float* __restrict__ qb, const float* __restrict__ kb,
    const float* __restrict__ vb, const float* __restrict__ ub,
    const float* __restrict__ tw, const float* __restrict__ tb,
    float* __restrict__ out) {
  __shared__ __align__(16) char smem[16896];
  float* Cs = (float*)smem;   // [16][261] f32 epilogue slab

  const int tid = threadIdx.x;
  const int lane = tid & 63;
  const int w = tid >> 6;            // wave id == weight id (0=q,1=k,2=v,3=u)
  const int l15 = lane & 15, lg = lane >> 4;
  const int xcd = blockIdx.x & 7;
  const int local = blockIdx.x >> 3;          // 0..255
  const int h = (xcd << 1) | (local & 1);     // h-interleave: same-s pair adjacent
  const int s0 = (local >> 1) << 7;

  f32x4 acc[8][4];
  for (int i = 0; i < 8; ++i)
    for (int j = 0; j < 4; ++j)
      for (int r = 0; r < 4; ++r) acc[i][j][r] = 0.f;

  const float* bp = (w == 0) ? qb : (w == 1) ? kb : (w == 2) ? vb : ub;
  float biasv[4];
  for (int fn = 0; fn < 4; ++fn) biasv[fn] = bp[h * 64 + fn * 16 + l15];

  // per-lane A base: row (s0 + l15), k-chunk lg; frag f adds f*16 rows
  const u16* ap = Xb + (size_t)(s0 + l15) * ND + (lg << 3);
  // per-lane B base: WT2[w][h][kc=lg][c=l15]; frag fn adds 16 cols; kt adds 4 kc
  const u16* bq = WT + (((size_t)(w * 16 + h)) << 16) + (lg << 9) + (l15 << 3);

#define LOAD_A(dst, kt) do { \
    _Pragma("unroll") \
    for (int f = 0; f < 8; ++f) \
      dst[f] = *(const short8v*)(ap + (size_t)f * (16 * ND) + ((kt) << 5)); \
  } while (0)

#define LOAD_B(dst, kt) do { \
    const u16* bb = bq + ((kt) << 11); \
    dst[0] = *(const short8v*)(bb); \
    dst[1] = *(const short8v*)(bb + 128); \
    dst[2] = *(const short8v*)(bb + 256); \
    dst[3] = *(const short8v*)(bb + 384); \
  } while (0)

#define MFMA32(af, bf) do { \
    __builtin_amdgcn_s_setprio(1); \
    _Pragma("unroll") \
    for (int fm = 0; fm < 8; ++fm) { \
      acc[fm][0] = __builtin_amdgcn_mfma_f32_16x16x32_bf16(af[fm], bf[0], acc[fm][0], 0, 0, 0); \
      acc[fm][1] = __builtin_amdgcn_mfma_f32_16x16x32_bf16(af[fm], bf[1], acc[fm][1], 0, 0, 0); \
      acc[fm][2] = __builtin_amdgcn_mfma_f32_16x16x32_bf16(af[fm], bf[2], acc[fm][2], 0, 0, 0); \
      acc[fm][3] = __builtin_amdgcn_mfma_f32_16x16x32_bf16(af[fm], bf[3], acc[fm][3], 0, 0, 0); \
    } \
    __builtin_amdgcn_s_setprio(0); \
  } while (0)

  short8v afE[8], afO[8], bfE[4], bfO[4];
  LOAD_A(afE, 0);
  LOAD_B(bfE, 0);
  for (int kt2 = 0; kt2 < 16; ++kt2) {
    const int e = kt2 << 1;
    // prefetch odd tile e+1 while computing even tile e
    LOAD_A(afO, e + 1);
    LOAD_B(bfO, e + 1);
    MFMA32(afE, bfE);
    // prefetch next even tile e+2 while computing odd tile e+1
    if (e + 2 < 32) {
      LOAD_A(afE, e + 2);
      LOAD_B(bfE, e + 2);
    }
    MFMA32(afO, bfO);
  }

  __syncthreads();  // first barrier since launch: waves converge for epilogue

  // epilogue: eight 16-token phases through Cs
#pragma unroll
  for (int ph = 0; ph < 8; ++ph) {
    for (int fn = 0; fn < 4; ++fn)
      for (int rr = 0; rr < 4; ++rr) {
        int rl = (lg << 2) + rr;
        int col = (w << 6) + (fn << 4) + l15;
        Cs[rl * 261 + col] = acc[ph][fn][rr] + biasv[fn];
      }
    __syncthreads();
    {
      int tloc = tid >> 4, o = tid & 15;
      int dbase = o << 2;
      int stok = s0 + (ph << 4) + tloc;
      int b = stok >> 13, seq = stok & 8191;
      const float* crow = Cs + tloc * 261;
      f32x4 fc = *(const f32x4*)(FC + ((size_t)seq << 6) + dbase);
      f32x4 vq = *(const f32x4*)(crow + dbase);
      f32x4 vk = *(const f32x4*)(crow + 64 + dbase);
      f32x4 vv = *(const f32x4*)(crow + 128 + dbase);
      f32x4 vu = *(const f32x4*)(crow + 192 + dbase);
      float sq = 0.f, sk = 0.f, su = 0.f;
      for (int j = 0; j < 4; ++j) {
        sq += vq[j] * vq[j]; sk += vk[j] * vk[j]; su += vu[j] * vu[j];
      }
      sq += __shfl_xor(sq, 1); sq += __shfl_xor(sq, 2);
      sq += __shfl_xor(sq, 4); sq += __shfl_xor(sq, 8);
      sk += __shfl_xor(sk, 1); sk += __shfl_xor(sk, 2);
      sk += __shfl_xor(sk, 4); sk += __shfl_xor(sk, 8);
      su += __shfl_xor(su, 1); su += __shfl_xor(su, 2);
      su += __shfl_xor(su, 4); su += __shfl_xor(su, 8);
      float qi = 1.f / fmaxf(sqrtf(sq), 1e-12f);
      float ki = 1.f / fmaxf(sqrtf(sk), 1e-12f);
      float ui = 1.f / fmaxf(sqrtf(su), 1e-12f);
      int p;
      if (seq < 256) p = ((seq >> 6) << 11) + (seq & 63);
      else { int v = seq - 256; int qc = v / 1984; p = (qc << 11) + 64 + (v - qc * 1984); }
      float* po = out + ((((size_t)(b * NH + h) << 13) + p) << 6) + dbase;
      f32x4 kr;
      kr[0] = vk[0] * ki * fc[0] - vk[1] * ki * fc[1];
      kr[1] = vk[0] * ki * fc[1] + vk[1] * ki * fc[0];
      kr[2] = vk[2] * ki * fc[2] - vk[3] * ki * fc[3];
      kr[3] = vk[2] * ki * fc[3] + vk[3] * ki * fc[2];
      *(f32x4*)(po + OUT_T) = kr;
      f32x4 df;
      float sd = 0.f, sdd = 0.f;
      for (int j = 0; j < 4; ++j) {
        df[j] = vv[j] - kr[j];
        sd += df[j]; sdd += df[j] * df[j];
      }
      sd += __shfl_xor(sd, 1); sd += __shfl_xor(sd, 2);
      sd += __shfl_xor(sd, 4); sd += __shfl_xor(sd, 8);
      sdd += __shfl_xor(sdd, 1); sdd += __shfl_xor(sdd, 2);
      sdd += __shfl_xor(sdd, 4); sdd += __shfl_xor(sdd, 8);
      float mean = sd * (1.f / 64.f);
      float var = (sdd - sd * sd * (1.f / 64.f)) * (1.f / 63.f);
      float istd = 1.f / (sqrtf(fmaxf(var, 0.f)) + 1e-8f);
      f32x4 twv = *(const f32x4*)(tw + h * 64 + dbase);
      f32x4 tbv = *(const f32x4*)(tb + h * 64 + dbase);
      f32x4 vo;
      for (int j = 0; j < 4; ++j)
        vo[j] = twv[j] * ((df[j] - mean) * istd) + tbv[j] + kr[j];
      *(f32x4*)(po + 2 * OUT_T) = vo;
      f32x4 qr;
      qr[0] = vq[0] * qi * fc[0] - vq[1] * qi * fc[1];
      qr[1] = vq[0] * qi * fc[1] + vq[1] * qi * fc[0];
      qr[2] = vq[2] * qi * fc[2] - vq[3] * qi * fc[3];
      qr[3] = vq[2] * qi * fc[3] + vq[3] * qi * fc[2];
      *(f32x4*)po = qr;
      qr[0] = vu[0] * ui * fc[0] - vu[1] * ui * fc[1];
      qr[1] = vu[0] * ui * fc[1] + vu[1] * ui * fc[0];
      qr[2] = vu[2] * ui * fc[2] - vu[3] * ui * fc[3];
      qr[3] = vu[2] * ui * fc[3] + vu[3] * ui * fc[2];
      *(f32x4*)(po + 3 * OUT_T) = qr;
    }
    __syncthreads();
  }
}

extern "C" void kernel_launch(void* const* d_in, const int* in_sizes, int n_in,
                              void* d_out, int out_size, void* d_ws, size_t ws_size,
                              hipStream_t stream) {
  const float* X  = (const float*)d_in[0];
  const float* FC = (const float*)d_in[1];
  const float* wq = (const float*)d_in[2];
  const float* qb = (const float*)d_in[3];
  const float* wk = (const float*)d_in[4];
  const float* kb = (const float*)d_in[5];
  const float* wv = (const float*)d_in[6];
  const float* vb = (const float*)d_in[7];
  const float* wu = (const float*)d_in[8];
  const float* ub = (const float*)d_in[9];
  const float* tw = (const float*)d_in[10];
  const float* tb = (const float*)d_in[11];
  const float* lw = (const float*)d_in[12];
  const float* lb = (const float*)d_in[13];
  float* out = (float*)d_out;
  u16* WT = (u16*)d_ws;                            // 8 MB: WT2[w][h][kc][c][8]
  u16* Xb = (u16*)((char*)d_ws + (8u << 20));      // 32 MB: 16384x1024 bf16

  hipLaunchKernelGGL(k_wt, dim3(1024), dim3(256), 0, stream, wq, wk, wv, wu, WT);
  hipLaunchKernelGGL(k_xbf, dim3(8192), dim3(256), 0, stream, X, Xb);
  hipLaunchKernelGGL(k_lr2, dim3(256), dim3(256), 0, stream, Xb, lw, lb, out);
  hipLaunchKernelGGL(k_main, dim3(2048), dim3(256), 0, stream,
                     Xb, FC, WT, qb, kb, vb, ub, tw, tb, out);
}

// Round 14
// 227.647 us; speedup vs baseline: 1.4804x; 1.4804x over previous
//
#include <hip/hip_runtime.h>

typedef unsigned int u32;
typedef unsigned short u16;
typedef short short8v __attribute__((ext_vector_type(8)));
typedef float f32x4 __attribute__((ext_vector_type(4)));

#define ND 1024
#define NH 16
#define OUT_T ((size_t)16777216)  // 2*16*8192*64 elements per stacked tensor

#define SBAR() __builtin_amdgcn_s_barrier()
#define VMW(n) asm volatile("s_waitcnt vmcnt(" #n ")" ::: "memory")
#define LGKM0() asm volatile("s_waitcnt lgkmcnt(0)" ::: "memory")
#define SCHED0() __builtin_amdgcn_sched_barrier(0)
#define PRIO1 __builtin_amdgcn_s_setprio(1)
#define PRIO0 __builtin_amdgcn_s_setprio(0)

__device__ __forceinline__ u16 f2bf(float f) {
  u32 u = __float_as_uint(f);
  u32 r = u + 0x7fffu + ((u >> 16) & 1u);
  return (u16)(r >> 16);
}

__device__ __forceinline__ short8v pack8(float4 a, float4 b) {
  short8v v;
  v[0] = (short)f2bf(a.x); v[1] = (short)f2bf(a.y);
  v[2] = (short)f2bf(a.z); v[3] = (short)f2bf(a.w);
  v[4] = (short)f2bf(b.x); v[5] = (short)f2bf(b.y);
  v[6] = (short)f2bf(b.z); v[7] = (short)f2bf(b.w);
  return v;
}

__device__ __forceinline__ void gload16(const void* g, void* l) {
  __builtin_amdgcn_global_load_lds((const __attribute__((address_space(1))) void*)g,
                                   (__attribute__((address_space(3))) void*)l, 16, 0, 0);
}

// ---- kernel 0: weights -> WT3[(w*16+h)][c 0..63][slot 0..127] bf16 ----
// pre-swizzled: slot (g*8+u) holds K-chunk (g*8 + (u ^ (c&7))) of column c
__global__ void k_wt(const float* __restrict__ w0, const float* __restrict__ w1,
                     const float* __restrict__ w2, const float* __restrict__ w3,
                     u16* __restrict__ WT) {
  __shared__ float T[64][65];
  int bid = blockIdx.x;
  int w = bid >> 8;
  int tk = (bid >> 4) & 15, tc = bid & 15;   // tc == head h
  const float* W = w == 0 ? w0 : w == 1 ? w1 : w == 2 ? w2 : w3;
  int k0 = tk << 6, c0 = tc << 6;
  int tid = threadIdx.x;
  for (int it = 0; it < 16; ++it) {
    int idx = it * 256 + tid;
    int kk = idx >> 6, cc = idx & 63;
    T[kk][cc] = W[(size_t)(k0 + kk) * ND + c0 + cc];
  }
  __syncthreads();
  for (int it = 0; it < 2; ++it) {
    int ci = it * 256 + tid;
    int cc = ci >> 3, k8 = ci & 7;
    short8v v;
    for (int j = 0; j < 8; ++j) v[j] = (short)f2bf(T[k8 * 8 + j][cc]);
    size_t off = ((size_t)((w * 16 + tc) * 64 + cc)) * 1024 +
                 ((tk << 3) + (k8 ^ (cc & 7))) * 8;
    *(short8v*)(WT + off) = v;
  }
}

// ---- kernel 0b: X f32 -> bf16 ----
__global__ void k_xbf(const float* __restrict__ X, u16* __restrict__ Xb) {
  size_t i = ((size_t)blockIdx.x * 256 + threadIdx.x) * 8;
  float4 a = *(const float4*)(X + i), b = *(const float4*)(X + i + 4);
  *(short8v*)(Xb + i) = pack8(a, b);
}

// ---- kernel 1: lr proj via MFMA + sigmoid + direct eta writes ----
__global__ __launch_bounds__(256) void k_lr2(const u16* __restrict__ Xb,
                                             const float* __restrict__ LW,
                                             const float* __restrict__ LB,
                                             float* __restrict__ out) {
  __shared__ __align__(16) char smem[46080];
  u16* LWs = (u16*)smem;
  u16* As = (u16*)(smem + 32768);
  float* El = (float*)(smem + 40960);
  const int tid = threadIdx.x, lane = tid & 63, wid = tid >> 6;
  const int l15 = lane & 15, lg = lane >> 4;
  const int n = blockIdx.x;
  const int tok0 = n << 6;

  {
    int row = tid >> 4;
    int cbase = (tid & 15) << 3;
    const float* src = LW + row * ND + (cbase << 3);
    for (int i = 0; i < 8; ++i) {
      float4 a = *(const float4*)(src + i * 8);
      float4 b = *(const float4*)(src + i * 8 + 4);
      int sc = (cbase + i) ^ (row & 7);
      *(short8v*)(LWs + row * 1024 + (sc << 3)) = pack8(a, b);
    }
  }

  const int arow0 = (wid << 4) + (lane >> 3);
  const u16* asrc = Xb + (size_t)(tok0 + arow0) * ND + ((((lane & 7) ^ arow0) & 7) << 3);
  const u32 aldo = wid << 10;
  const int aoff = ((wid << 4) + l15) << 6;
  const int key = l15 & 7;

  f32x4 acc;
  for (int r = 0; r < 4; ++r) acc[r] = 0.f;
  __syncthreads();

  for (int kt = 0; kt < 16; ++kt) {
    gload16(asrc + (kt << 6), As + aldo);
    gload16(asrc + (kt << 6) + 8 * ND, As + aldo + 512);
    __syncthreads();
    for (int ks = 0; ks < 2; ++ks) {
      int kcl = (ks << 2) + lg;
      int kcg = (kt << 3) + kcl;
      short8v af = *(const short8v*)(As + aoff + ((kcl ^ key) << 3));
      short8v bf = *(const short8v*)(LWs + (l15 << 10) + ((kcg ^ key) << 3));
      acc = __builtin_amdgcn_mfma_f32_16x16x32_bf16(af, bf, acc, 0, 0, 0);
    }
    __syncthreads();
  }

  for (int rr = 0; rr < 4; ++rr) {
    float v = acc[rr] + LB[l15];
    float e = (1.f / (1.f + expf(-v))) * (1.f / 4096.f);
    El[l15 * 72 + (wid << 4) + (lg << 2) + rr] = e;
  }
  __syncthreads();

  const int b = n >> 7, nl = n & 127;
  int q, rc;
  if (nl < 4) { q = nl; rc = 0; }
  else { q = (nl - 4) / 31; rc = nl - 3 - 31 * q; }
  const int pc = q * 32 + rc;
  const int j = tid >> 2, kq = tid & 3;
  size_t base = 4 * OUT_T + (((size_t)(b * NH) << 13) + (pc << 6)) * 64 + (size_t)j * 64;
  for (int h = 0; h < 16; ++h) {
    float* po = out + base + ((size_t)h << 19);
    for (int qq = 0; qq < 4; ++qq) {
      int k0 = (kq + (qq << 2)) << 2;
      const float* ep = El + h * 72 + k0;
      f32x4 t; t[0] = ep[0]; t[1] = ep[1]; t[2] = ep[2]; t[3] = ep[3];
      *(f32x4*)(po + k0) = t;
    }
  }
}

// ---- kernel 2: faithful 8-phase template (m201 port), fused epilogue ----
// 512 thr (8 waves 2x4), tile 256 tok x 256 col, BK=64, 128KB LDS dbuf.
// buf0 = even K-steps, buf1 = odd. vmcnt(4) at phases 4/8 only.
__global__ __launch_bounds__(512, 2) void k_main(
    const u16* __restrict__ Xb, const float* __restrict__ FC,
    const u16* __restrict__ WT,
    const float* __restrict__ qb, const float* __restrict__ kb,
    const float* __restrict__ vb, const float* __restrict__ ub,
    const float* __restrict__ tw, const float* __restrict__ tb,
    float* __restrict__ out) {
  __shared__ __align__(16) char smem[131072];
  float* Cs = (float*)smem;  // epilogue slab [64][261] f32, aliases post-K

  const int tid = threadIdx.x;
  const int lane = tid & 63;
  const int wid = tid >> 6;
  const int wm = wid >> 2, wn = wid & 3;
  const int l15 = lane & 15, lg = lane >> 4;
  const int xcd = blockIdx.x & 7;
  const int local = blockIdx.x >> 3;          // 0..127
  const int h = (xcd << 1) | (local & 1);     // h-interleave on XCD (r12 win)
  const int s0 = (local >> 1) << 8;

  f32x4 acc[8][4];
  for (int i = 0; i < 8; ++i)
    for (int j = 0; j < 4; ++j)
      for (int r = 0; r < 4; ++r) acc[i][j][r] = 0.f;

  const float* bp = (wn == 0) ? qb : (wn == 1) ? kb : (wn == 2) ? vb : ub;
  float biasv[4];
  for (int fn = 0; fn < 4; ++fn) biasv[fn] = bp[h * 64 + fn * 16 + l15];

  // staging sources (per-thread)
  const u16* asrc_t = Xb + (size_t)(s0 + (tid >> 3)) * ND +
                      (((tid & 7) ^ ((tid >> 3) & 7)) << 3);
  const u16* bsrc_t = WT + ((size_t)h * 64 + (tid >> 3)) * 1024 + ((tid & 7) << 3);
  const u32 awo = wid << 9;  // wave-uniform dest offset (u16)

  // frag read offsets (u16, within buffer)
  int aoff[8], boff[4], akx[2];
  for (int f = 0; f < 8; ++f) aoff[f] = ((wm << 7) + (f << 4) + l15) << 6;
  for (int f = 0; f < 4; ++f) boff[f] = 16384 + (((wn << 6) + (f << 4) + l15) << 6);
  for (int ks = 0; ks < 2; ++ks) akx[ks] = (((ks << 2) + lg) ^ (l15 & 7)) << 3;

#define STAGE_A(b, t, hf) do { \
    gload16(asrc_t + (size_t)(((hf) << 7)) * ND + ((t) << 6), \
            (u16*)smem + ((b) << 15) + ((hf) << 13) + awo); \
    gload16(asrc_t + (size_t)(((hf) << 7) + 64) * ND + ((t) << 6), \
            (u16*)smem + ((b) << 15) + ((hf) << 13) + 4096 + awo); \
  } while (0)

#define STAGE_B(b, t, hf) do { \
    gload16(bsrc_t + (size_t)((hf) * 2) * 1048576 + ((t) << 6), \
            (u16*)smem + ((b) << 15) + 16384 + ((hf) << 13) + awo); \
    gload16(bsrc_t + (size_t)((hf) * 2 + 1) * 1048576 + ((t) << 6), \
            (u16*)smem + ((b) << 15) + 16384 + ((hf) << 13) + 4096 + awo); \
  } while (0)

#define RD_A4(dst, b, flo) do { \
    const u16* _p = (const u16*)smem + ((b) << 15); \
    _Pragma("unroll") \
    for (int f = 0; f < 4; ++f) \
      _Pragma("unroll") \
      for (int ks = 0; ks < 2; ++ks) \
        dst[f][ks] = *(const short8v*)(_p + aoff[(flo) + f] + akx[ks]); \
  } while (0)

#define RD_B2(dst, b, flo) do { \
    const u16* _p = (const u16*)smem + ((b) << 15); \
    _Pragma("unroll") \
    for (int f = 0; f < 2; ++f) \
      _Pragma("unroll") \
      for (int ks = 0; ks < 2; ++ks) \
        dst[f][ks] = *(const short8v*)(_p + boff[(flo) + f] + akx[ks]); \
  } while (0)

#define MM(af, bf, fmb, fnb) do { \
    PRIO1; \
    _Pragma("unroll") \
    for (int fm = 0; fm < 4; ++fm) \
      _Pragma("unroll") \
      for (int fn = 0; fn < 2; ++fn) \
        _Pragma("unroll") \
        for (int ks = 0; ks < 2; ++ks) \
          acc[(fmb) + fm][(fnb) + fn] = __builtin_amdgcn_mfma_f32_16x16x32_bf16( \
              af[fm][ks], bf[fn][ks], acc[(fmb) + fm][(fnb) + fn], 0, 0, 0); \
    PRIO0; \
  } while (0)

  // prologue: buf0 <- K0 (B,A), buf1 <- K1 (B only)
  STAGE_B(0, 0, 0); STAGE_B(0, 0, 1);
  STAGE_A(0, 0, 0); STAGE_A(0, 0, 1);
  STAGE_B(1, 1, 0); STAGE_B(1, 1, 1);
  VMW(4);   // buf0 complete; buf1.B may fly
  SBAR();

  short8v afA[4][2], afB[4][2], bfL[2][2], bfH[2][2];
  for (int i = 0; i < 8; ++i) {
    const int e = i << 1;
    // P1: read buf0 A-lo + B-lo; stage buf1.A0(e+1)
    RD_A4(afA, 0, 0);
    RD_B2(bfL, 0, 0);
    STAGE_A(1, e + 1, 0);
    SBAR(); LGKM0(); SCHED0();
    MM(afA, bfL, 0, 0);
    SBAR();
    // P2: read buf0 B-hi; stage buf1.A1(e+1)
    RD_B2(bfH, 0, 2);
    STAGE_A(1, e + 1, 1);
    SBAR(); LGKM0(); SCHED0();
    MM(afA, bfH, 0, 2);
    SBAR();
    // P3: read buf0 A-hi; stage buf0.B0(e+2)
    RD_A4(afB, 0, 4);
    if (i < 7) STAGE_B(0, e + 2, 0);
    SBAR(); LGKM0(); SCHED0();
    MM(afB, bfL, 4, 0);
    SBAR();
    // P4: stage buf0.B1(e+2); MFMA; counted vmcnt
    if (i < 7) STAGE_B(0, e + 2, 1);
    MM(afB, bfH, 4, 2);
    if (i < 7) { VMW(4); } else { VMW(0); }
    SBAR();
    // P5: read buf1 A-lo + B-lo (K e+1); stage buf0.A0(e+2)
    RD_A4(afA, 1, 0);
    RD_B2(bfL, 1, 0);
    if (i < 7) STAGE_A(0, e + 2, 0);
    SBAR(); LGKM0(); SCHED0();
    MM(afA, bfL, 0, 0);
    SBAR();
    // P6: read buf1 B-hi; stage buf0.A1(e+2)
    RD_B2(bfH, 1, 2);
    if (i < 7) STAGE_A(0, e + 2, 1);
    SBAR(); LGKM0(); SCHED0();
    MM(afA, bfH, 0, 2);
    SBAR();
    // P7: read buf1 A-hi; stage buf1.B0(e+3)
    RD_A4(afB, 1, 4);
    if (i < 7) STAGE_B(1, e + 3, 0);
    SBAR(); LGKM0(); SCHED0();
    MM(afB, bfL, 4, 0);
    SBAR();
    // P8: stage buf1.B1(e+3); MFMA; counted vmcnt
    if (i < 7) STAGE_B(1, e + 3, 1);
    MM(afB, bfH, 4, 2);
    if (i < 7) { VMW(4); }
    SBAR();
  }
  VMW(0); LGKM0();
  SBAR();  // safe to alias Cs

  // epilogue: four 64-token phases through Cs (r5-verified)
  for (int ph = 0; ph < 4; ++ph) {
    if (wm == (ph >> 1)) {
      for (int f2 = 0; f2 < 4; ++f2) {
        int fm = ((ph & 1) << 2) + f2;
        for (int fn = 0; fn < 4; ++fn)
          for (int rr = 0; rr < 4; ++rr) {
            int rl = (f2 << 4) + (lg << 2) + rr;
            int col = (wn << 6) + (fn << 4) + l15;
            Cs[rl * 261 + col] = acc[fm][fn][rr] + biasv[fn];
          }
      }
    }
    __syncthreads();
    {
      int tloc = tid >> 3, o = tid & 7;
      int dbase = o << 3;
      int stok = s0 + (ph << 6) + tloc;
      int b = stok >> 13, seq = stok & 8191;
      const float* crow = Cs + tloc * 261;
      float fc[8];
      {
        const f32x4* fp = (const f32x4*)(FC + ((size_t)seq << 6) + dbase);
        f32x4 t0 = fp[0], t1 = fp[1];
        fc[0] = t0[0]; fc[1] = t0[1]; fc[2] = t0[2]; fc[3] = t0[3];
        fc[4] = t1[0]; fc[5] = t1[1]; fc[6] = t1[2]; fc[7] = t1[3];
      }
      float sq = 0.f, sk = 0.f, su = 0.f;
      for (int j = 0; j < 8; ++j) {
        float a = crow[dbase + j], b2 = crow[64 + dbase + j], c = crow[192 + dbase + j];
        sq += a * a; sk += b2 * b2; su += c * c;
      }
      sq += __shfl_xor(sq, 1); sq += __shfl_xor(sq, 2); sq += __shfl_xor(sq, 4);
      sk += __shfl_xor(sk, 1); sk += __shfl_xor(sk, 2); sk += __shfl_xor(sk, 4);
      su += __shfl_xor(su, 1); su += __shfl_xor(su, 2); su += __shfl_xor(su, 4);
      float qi = 1.f / fmaxf(sqrtf(sq), 1e-12f);
      float ki = 1.f / fmaxf(sqrtf(sk), 1e-12f);
      float ui = 1.f / fmaxf(sqrtf(su), 1e-12f);
      int p;
      if (seq < 256) p = ((seq >> 6) << 11) + (seq & 63);
      else { int v = seq - 256; int qc = v / 1984; p = (qc << 11) + 64 + (v - qc * 1984); }
      float* po = out + ((((size_t)(b * NH + h) << 13) + p) << 6) + dbase;
      float kr[8];
      for (int jj = 0; jj < 4; ++jj) {
        float xa = crow[64 + dbase + 2*jj] * ki, xb = crow[64 + dbase + 2*jj + 1] * ki;
        float c = fc[2*jj], s = fc[2*jj+1];
        kr[2*jj]     = xa * c - xb * s;
        kr[2*jj + 1] = xa * s + xb * c;
      }
      for (int i2 = 0; i2 < 2; ++i2) {
        f32x4 t; t[0] = kr[4*i2]; t[1] = kr[4*i2+1]; t[2] = kr[4*i2+2]; t[3] = kr[4*i2+3];
        *(f32x4*)(po + OUT_T + 4*i2) = t;
      }
      float sd = 0.f, sdd = 0.f, df[8];
      for (int j = 0; j < 8; ++j) {
        df[j] = crow[128 + dbase + j] - kr[j];
        sd += df[j]; sdd += df[j] * df[j];
      }
      sd += __shfl_xor(sd, 1); sd += __shfl_xor(sd, 2); sd += __shfl_xor(sd, 4);
      sdd += __shfl_xor(sdd, 1); sdd += __shfl_xor(sdd, 2); sdd += __shfl_xor(sdd, 4);
      float mean = sd * (1.f / 64.f);
      float var = (sdd - sd * sd * (1.f / 64.f)) * (1.f / 63.f);
      float istd = 1.f / (sqrtf(fmaxf(var, 0.f)) + 1e-8f);
      for (int j = 0; j < 8; ++j) {
        int d = dbase + j;
        df[j] = tw[h * 64 + d] * ((df[j] - mean) * istd) + tb[h * 64 + d] + kr[j];
      }
      for (int i2 = 0; i2 < 2; ++i2) {
        f32x4 t; t[0] = df[4*i2]; t[1] = df[4*i2+1]; t[2] = df[4*i2+2]; t[3] = df[4*i2+3];
        *(f32x4*)(po + 2 * OUT_T + 4*i2) = t;
      }
      float qr[8];
      for (int jj = 0; jj < 4; ++jj) {
        float xa = crow[dbase + 2*jj] * qi, xb = crow[dbase + 2*jj + 1] * qi;
        float c = fc[2*jj], s = fc[2*jj+1];
        qr[2*jj]     = xa * c - xb * s;
        qr[2*jj + 1] = xa * s + xb * c;
      }
      for (int i2 = 0; i2 < 2; ++i2) {
        f32x4 t; t[0] = qr[4*i2]; t[1] = qr[4*i2+1]; t[2] = qr[4*i2+2]; t[3] = qr[4*i2+3];
        *(f32x4*)(po + 4*i2) = t;
      }
      for (int jj = 0; jj < 4; ++jj) {
        float xa = crow[192 + dbase + 2*jj] * ui, xb = crow[192 + dbase + 2*jj + 1] * ui;
        float c = fc[2*jj], s = fc[2*jj+1];
        qr[2*jj]     = xa * c - xb * s;
        qr[2*jj + 1] = xa * s + xb * c;
      }
      for (int i2 = 0; i2 < 2; ++i2) {
        f32x4 t; t[0] = qr[4*i2]; t[1] = qr[4*i2+1]; t[2] = qr[4*i2+2]; t[3] = qr[4*i2+3];
        *(f32x4*)(po + 3 * OUT_T + 4*i2) = t;
      }
    }
    __syncthreads();
  }
}

extern "C" void kernel_launch(void* const* d_in, const int* in_sizes, int n_in,
                              void* d_out, int out_size, void* d_ws, size_t ws_size,
                              hipStream_t stream) {
  const float* X  = (const float*)d_in[0];
  const float* FC = (const float*)d_in[1];
  const float* wq = (const float*)d_in[2];
  const float* qb = (const float*)d_in[3];
  const float* wk = (const float*)d_in[4];
  const float* kb = (const float*)d_in[5];
  const float* wv = (const float*)d_in[6];
  const float* vb = (const float*)d_in[7];
  const float* wu = (const float*)d_in[8];
  const float* ub = (const float*)d_in[9];
  const float* tw = (const float*)d_in[10];
  const float* tb = (const float*)d_in[11];
  const float* lw = (const float*)d_in[12];
  const float* lb = (const float*)d_in[13];
  float* out = (float*)d_out;
  u16* WT = (u16*)d_ws;                            // 8 MB: WT3 pre-swizzled
  u16* Xb = (u16*)((char*)d_ws + (8u << 20));      // 32 MB: 16384x1024 bf16

  hipLaunchKernelGGL(k_wt, dim3(1024), dim3(256), 0, stream, wq, wk, wv, wu, WT);
  hipLaunchKernelGGL(k_xbf, dim3(8192), dim3(256), 0, stream, X, Xb);
  hipLaunchKernelGGL(k_lr2, dim3(256), dim3(256), 0, stream, Xb, lw, lb, out);
  hipLaunchKernelGGL(k_main, dim3(1024), dim3(512), 0, stream,
                     Xb, FC, WT, qb, kb, vb, ub, tw, tb, out);
}